// Round 7
// baseline (112807.471 us; speedup 1.0000x reference)
//
#include <hip/hip_runtime.h>
#include <math.h>

namespace {

constexpr int TT  = 256;   // timesteps
constexpr int HH  = 512;   // hidden

// ws layout (floats) — total ~3 MB
constexpr size_t OFF_H0 = 0;
constexpr size_t OFF_C0 = (size_t)1 * HH * 64;
constexpr size_t OFF_H1 = (size_t)2 * HH * 64;
constexpr size_t OFF_C1 = (size_t)3 * HH * 64;
constexpr size_t OFF_Z  = (size_t)4 * HH * 64;   // feat z    [1024][64]
constexpr size_t OFF_S  = OFF_Z + 65536;         // feat silu [1024][64]
constexpr size_t OFF_B  = OFF_S + 65536;         // feat bas  [1024][8][64]
constexpr size_t WS_NEED = (OFF_B + 524288) * 4; // bytes

// Cox-de Boor, GRID_SIZE=5, ORDER=3 -> 12 knots, 8 basis functions.
__device__ __forceinline__ void bspline8(float x, float* out) {
    const float KG[12] = {-2.2f,-1.8f,-1.4f,-1.0f,-0.6f,-0.2f,
                           0.2f, 0.6f, 1.0f, 1.4f, 1.8f, 2.2f};
    float b[11];
#pragma unroll
    for (int i = 0; i < 11; ++i)
        b[i] = (x >= KG[i] && x < KG[i + 1]) ? 1.0f : 0.0f;
#pragma unroll
    for (int p = 1; p <= 3; ++p) {
#pragma unroll
        for (int i = 0; i + p < 11; ++i) {
            float l = (x - KG[i])         * (1.0f / (KG[i + p] - KG[i]));
            float r = (KG[i + p + 1] - x) * (1.0f / (KG[i + p + 1] - KG[i + 1]));
            b[i] = l * b[i] + r * b[i + 1];   // ascending: reads old b[i], old b[i+1]
        }
    }
#pragma unroll
    for (int i = 0; i < 8; ++i) out[i] = b[i];
}

__global__ __launch_bounds__(256) void zero_state(float* s) {
    s[blockIdx.x * 256 + threadIdx.x] = 0.0f;   // grid=512 covers h0,c0,h1,c1
}

__global__ __launch_bounds__(256) void sentinel_kernel(float* out, float v) {
    int i = blockIdx.x * 256 + threadIdx.x;
    if (i < 8192) out[i] = v;
}

// Features of cat([inp, h]) for one (t, layer): z, silu(z), bases -> [k][b].
template <int IN, bool XS>
__global__ __launch_bounds__(256) void feat_kernel(
    const float* __restrict__ src, int t, const float* __restrict__ hT,
    float* __restrict__ fz, float* __restrict__ fs, float* __restrict__ fb)
{
    const int g = blockIdx.x * 256 + threadIdx.x;   // [0, (IN+512)*64)
    const int k = g >> 6, b = g & 63;
    float z;
    if (k < IN) z = XS ? src[((size_t)b * TT + t) * IN + k] : src[(size_t)k * 64 + b];
    else        z = hT[(size_t)(k - IN) * 64 + b];
    fz[g] = z;
    fs[g] = z / (1.0f + expf(-z));     // silu
    float bs[8];
    bspline8(z, bs);
#pragma unroll
    for (int r = 0; r < 8; ++r) fb[((size_t)k * 8 + r) * 64 + b] = bs[r];
}

// Fused gates+KAN+update for one (t, layer). One thread per (o, b); o wave-uniform.
template <int IN>
__global__ __launch_bounds__(256) void cell_kernel(
    const float* __restrict__ fz, const float* __restrict__ fs,
    const float* __restrict__ fb,
    const float* __restrict__ w_ih,   // [1536][IN]
    const float* __restrict__ w_hh,   // [1536][512]
    const float* __restrict__ bw,     // [512][W]
    const float* __restrict__ sw,     // [512][W][8]
    const float* __restrict__ b_ih, const float* __restrict__ b_hh,
    float* __restrict__ hT, float* __restrict__ cT)
{
    constexpr int W = IN + 512;
    const int gid = blockIdx.x * 256 + threadIdx.x;   // 32768 = 512*64
    const int o = gid >> 6, b = gid & 63;

    float si = 0.f, sf = 0.f, so = 0.f;
#pragma unroll 4
    for (int k = 0; k < IN; ++k) {                    // input part of gates
        float z = fz[(size_t)k * 64 + b];
        si = fmaf(z, w_ih[(size_t)(o       ) * IN + k], si);
        sf = fmaf(z, w_ih[(size_t)(o +  512) * IN + k], sf);
        so = fmaf(z, w_ih[(size_t)(o + 1024) * IN + k], so);
    }
#pragma unroll 4
    for (int k = 0; k < 512; ++k) {                   // hidden part of gates
        float z = fz[(size_t)(IN + k) * 64 + b];
        si = fmaf(z, w_hh[(size_t)(o       ) * 512 + k], si);
        sf = fmaf(z, w_hh[(size_t)(o +  512) * 512 + k], sf);
        so = fmaf(z, w_hh[(size_t)(o + 1024) * 512 + k], so);
    }
    float sg = 0.f;
#pragma unroll 2
    for (int k = 0; k < W; ++k) {                     // KAN: silu + spline branches
        sg = fmaf(fs[(size_t)k * 64 + b], bw[(size_t)o * W + k], sg);
        const float* sp = sw + ((size_t)o * W + k) * 8;
        const float* bb = fb + ((size_t)k * 8) * 64 + b;
#pragma unroll
        for (int r = 0; r < 8; ++r) sg = fmaf(bb[(size_t)r * 64], sp[r], sg);
    }
    si += b_ih[o] + b_hh[o];
    sf += b_ih[o + 512] + b_hh[o + 512];
    so += b_ih[o + 1024] + b_hh[o + 1024];
    float ig = 1.0f / (1.0f + expf(-si));
    float fg = 1.0f / (1.0f + expf(-sf));
    float og = 1.0f / (1.0f + expf(-so));
    float c = fg * cT[(size_t)o * 64 + b] + ig * sg;
    cT[(size_t)o * 64 + b] = c;
    hT[(size_t)o * 64 + b] = og * tanhf(c);
}

// out[b][jo] = sum_o h1[o][b] * fc_w[jo][o] + fc_b[jo] — FP32 output!
__global__ __launch_bounds__(256) void final_fc(
    const float* __restrict__ hT1, const float* __restrict__ fc_w,
    const float* __restrict__ fc_b, float* __restrict__ out)
{
    const int gid = blockIdx.x * 256 + threadIdx.x;   // 8192 = 64*128
    const int b = gid & 63, jo = gid >> 6;
    float a = fc_b[jo];
    for (int o = 0; o < 512; ++o)
        a = fmaf(hT1[(size_t)o * 64 + b], fc_w[(size_t)jo * 512 + o], a);
    out[(size_t)b * 128 + jo] = a;
}

} // namespace

extern "C" void kernel_launch(void* const* d_in, const int* in_sizes, int n_in,
                              void* d_out, int out_size, void* d_ws, size_t ws_size,
                              hipStream_t stream) {
    (void)out_size;
    float* out = (float*)d_out;

    static const int EXP_SIZES[15] = {
        64 * 256 * 128, 1536 * 128, 1536 * 512, 1536, 1536,
        512 * 640, 512 * 640 * 8,
        1536 * 512, 1536 * 512, 1536, 1536,
        512 * 1024, 512 * 1024 * 8,
        128 * 512, 128
    };
    if (n_in != 15) { sentinel_kernel<<<32, 256, 0, stream>>>(out, 111.0f); return; }
    for (int i = 0; i < 15; ++i)
        if (in_sizes[i] != EXP_SIZES[i]) {
            sentinel_kernel<<<32, 256, 0, stream>>>(out, 200.0f * (i + 1)); return;
        }
    if (ws_size < WS_NEED) { sentinel_kernel<<<32, 256, 0, stream>>>(out, 7777.0f); return; }

    const float* x        = (const float*)d_in[0];
    const float* w_ih0    = (const float*)d_in[1];
    const float* w_hh0    = (const float*)d_in[2];
    const float* b_ih0    = (const float*)d_in[3];
    const float* b_hh0    = (const float*)d_in[4];
    const float* kbase0   = (const float*)d_in[5];
    const float* kspline0 = (const float*)d_in[6];
    const float* w_ih1    = (const float*)d_in[7];
    const float* w_hh1    = (const float*)d_in[8];
    const float* b_ih1    = (const float*)d_in[9];
    const float* b_hh1    = (const float*)d_in[10];
    const float* kbase1   = (const float*)d_in[11];
    const float* kspline1 = (const float*)d_in[12];
    const float* fc_w     = (const float*)d_in[13];
    const float* fc_b     = (const float*)d_in[14];

    float* ws = (float*)d_ws;
    float* h0 = ws + OFF_H0;
    float* c0 = ws + OFF_C0;
    float* h1 = ws + OFF_H1;
    float* c1 = ws + OFF_C1;
    float* fz = ws + OFF_Z;
    float* fs = ws + OFF_S;
    float* fb = ws + OFF_B;

    zero_state<<<512, 256, 0, stream>>>(h0);   // h0,c0,h1,c1 contiguous

    for (int t = 0; t < TT; ++t) {
        // ---- layer 0 (In=128, W=640) ----
        feat_kernel<128, true><<<160, 256, 0, stream>>>(x, t, h0, fz, fs, fb);
        cell_kernel<128><<<128, 256, 0, stream>>>(
            fz, fs, fb, w_ih0, w_hh0, kbase0, kspline0, b_ih0, b_hh0, h0, c0);
        // ---- layer 1 (In=512, W=1024) ----
        feat_kernel<512, false><<<256, 256, 0, stream>>>(h0, t, h1, fz, fs, fb);
        cell_kernel<512><<<128, 256, 0, stream>>>(
            fz, fs, fb, w_ih1, w_hh1, kbase1, kspline1, b_ih1, b_hh1, h1, c1);
    }

    final_fc<<<32, 256, 0, stream>>>(h1, fc_w, fc_b, out);
}

// Round 8
// 30700.735 us; speedup vs baseline: 3.6744x; 3.6744x over previous
//
#include <hip/hip_runtime.h>
#include <math.h>

namespace {

constexpr int TT = 256;   // timesteps
constexpr int HH = 512;   // hidden

// ---- ws layout (floats) ----
constexpr size_t OFF_H0   = 0;                       // [512][64]
constexpr size_t OFF_C0   = 32768;
constexpr size_t OFF_H1   = 65536;
constexpr size_t OFF_C1   = 98304;
constexpr size_t OFF_FZ0  = 131072;                  // [640][64]
constexpr size_t OFF_FS0  = OFF_FZ0 + 40960;
constexpr size_t OFF_FB0  = OFF_FS0 + 40960;         // [640][8][64]
constexpr size_t OFF_FZ1  = OFF_FB0 + 327680;        // [1024][64]
constexpr size_t OFF_FS1  = OFF_FZ1 + 65536;
constexpr size_t OFF_FB1  = OFF_FS1 + 65536;         // [1024][8][64]
constexpr size_t OFF_P    = OFF_FB1 + 524288;        // [12288][64]
constexpr size_t OFF_SWT0 = OFF_P + 786432;          // [8][512][640]
constexpr size_t OFF_SWT1 = OFF_SWT0 + 2621440;      // [8][512][1024]
constexpr size_t WS_NEED  = (OFF_SWT1 + 4194304) * 4;   // ~35.2 MB

__device__ __forceinline__ float sigmoidf_(float v) { return 1.0f / (1.0f + expf(-v)); }

// Cox-de Boor, GRID_SIZE=5, ORDER=3 -> 12 knots, 8 basis functions. (verified)
__device__ __forceinline__ void bspline8(float x, float* out) {
    const float KG[12] = {-2.2f,-1.8f,-1.4f,-1.0f,-0.6f,-0.2f,
                           0.2f, 0.6f, 1.0f, 1.4f, 1.8f, 2.2f};
    float b[11];
#pragma unroll
    for (int i = 0; i < 11; ++i)
        b[i] = (x >= KG[i] && x < KG[i + 1]) ? 1.0f : 0.0f;
#pragma unroll
    for (int p = 1; p <= 3; ++p) {
#pragma unroll
        for (int i = 0; i + p < 11; ++i) {
            float l = (x - KG[i])         * (1.0f / (KG[i + p] - KG[i]));
            float r = (KG[i + p + 1] - x) * (1.0f / (KG[i + p + 1] - KG[i + 1]));
            b[i] = l * b[i] + r * b[i + 1];
        }
    }
#pragma unroll
    for (int i = 0; i < 8; ++i) out[i] = b[i];
}

__global__ __launch_bounds__(256) void zero_state(float* s) {
    s[blockIdx.x * 256 + threadIdx.x] = 0.0f;   // grid=512: h0,c0,h1,c1
}

__global__ __launch_bounds__(256) void sentinel_kernel(float* out, float v) {
    int i = blockIdx.x * 256 + threadIdx.x;
    if (i < 8192) out[i] = v;
}

// sw [512][W][8] -> swT [8][512][W]  (contiguous k for float4 broadcast loads)
template <int W>
__global__ __launch_bounds__(256) void transpose_sw(const float* __restrict__ sw,
                                                    float* __restrict__ swT) {
    const int i = blockIdx.x * 256 + threadIdx.x;   // over 512*W
    float v[8];
#pragma unroll
    for (int r = 0; r < 8; ++r) v[r] = sw[(size_t)i * 8 + r];
#pragma unroll
    for (int r = 0; r < 8; ++r) swT[(size_t)r * 512 * W + i] = v[r];
}

// ---------------- GEMM: 12288 items of K=W/2, 4 rows/wave sharing features ---
// item space (per kc chunk, 6144 subs): [0,1536) gate rows; [1536,2048) silu
// rows; [2048,6144) spline (r = (s-2048)>>9, o = (s-2048)&511).
// Wave w (0..3071): kc = w>=1536, sub4 = (w - kc*1536)*4 -> 4 consecutive subs
// (always same type, same r, same kc). lane = batch. Writes p[item][64].
template <int IN>
__global__ __launch_bounds__(256) void gemm_kernel(
    const float* __restrict__ fz, const float* __restrict__ fs,
    const float* __restrict__ fb,
    const float* __restrict__ w_ih,   // [1536][IN]
    const float* __restrict__ w_hh,   // [1536][512]
    const float* __restrict__ bw,     // [512][W]
    const float* __restrict__ swT,    // [8][512][W]
    float* __restrict__ p)            // [12288][64]
{
    constexpr int W  = IN + 512;
    constexpr int KC = W / 2;
    const int lane = threadIdx.x & 63;
    const int wid  = blockIdx.x * 4 + (threadIdx.x >> 6);   // 0..3071
    const int kc   = (wid >= 1536) ? 1 : 0;
    const int sub4 = (wid - kc * 1536) * 4;
    const int kbeg = kc * KC, kend = kbeg + KC;

    float acc[4] = {0.f, 0.f, 0.f, 0.f};

    if (sub4 < 1536) {
        // ---- gate rows: z features, w_ih | w_hh segments ----
        const int j0 = sub4;
        {   // segment over w_ih: [kbeg, min(kend, IN))
            const int bnd = (kend < IN) ? kend : IN;
            for (int k = kbeg; k < bnd; k += 8) {
                float f8[8];
#pragma unroll
                for (int u = 0; u < 8; ++u) f8[u] = fz[(size_t)(k + u) * 64 + lane];
#pragma unroll
                for (int j = 0; j < 4; ++j) {
                    const float* wp = w_ih + (size_t)(j0 + j) * IN + k;
                    float4 wa = *(const float4*)wp;
                    float4 wb = *(const float4*)(wp + 4);
                    acc[j] = fmaf(f8[0], wa.x, acc[j]); acc[j] = fmaf(f8[1], wa.y, acc[j]);
                    acc[j] = fmaf(f8[2], wa.z, acc[j]); acc[j] = fmaf(f8[3], wa.w, acc[j]);
                    acc[j] = fmaf(f8[4], wb.x, acc[j]); acc[j] = fmaf(f8[5], wb.y, acc[j]);
                    acc[j] = fmaf(f8[6], wb.z, acc[j]); acc[j] = fmaf(f8[7], wb.w, acc[j]);
                }
            }
        }
        {   // segment over w_hh: [max(kbeg, IN), kend)
            const int a = (kbeg > IN) ? kbeg : IN;
            for (int k = a; k < kend; k += 8) {
                float f8[8];
#pragma unroll
                for (int u = 0; u < 8; ++u) f8[u] = fz[(size_t)(k + u) * 64 + lane];
#pragma unroll
                for (int j = 0; j < 4; ++j) {
                    const float* wp = w_hh + (size_t)(j0 + j) * 512 + (k - IN);
                    float4 wa = *(const float4*)wp;
                    float4 wb = *(const float4*)(wp + 4);
                    acc[j] = fmaf(f8[0], wa.x, acc[j]); acc[j] = fmaf(f8[1], wa.y, acc[j]);
                    acc[j] = fmaf(f8[2], wa.z, acc[j]); acc[j] = fmaf(f8[3], wa.w, acc[j]);
                    acc[j] = fmaf(f8[4], wb.x, acc[j]); acc[j] = fmaf(f8[5], wb.y, acc[j]);
                    acc[j] = fmaf(f8[6], wb.z, acc[j]); acc[j] = fmaf(f8[7], wb.w, acc[j]);
                }
            }
        }
    } else {
        // ---- silu / spline rows: single contiguous weight array ----
        const float* fptr; int fst;
        const float* wrow[4];
        if (sub4 < 2048) {
            const int o0 = sub4 - 1536;
            fptr = fs; fst = 64;
#pragma unroll
            for (int j = 0; j < 4; ++j) wrow[j] = bw + (size_t)(o0 + j) * W + kbeg;
        } else {
            const int s = sub4 - 2048, r = s >> 9, o0 = s & 511;
            fptr = fb + r * 64; fst = 512;
#pragma unroll
            for (int j = 0; j < 4; ++j)
                wrow[j] = swT + ((size_t)r * 512 + o0 + j) * W + kbeg;
        }
        for (int k = kbeg; k < kend; k += 8) {
            float f8[8];
#pragma unroll
            for (int u = 0; u < 8; ++u) f8[u] = fptr[(size_t)(k + u) * fst + lane];
#pragma unroll
            for (int j = 0; j < 4; ++j) {
                const float* wp = wrow[j] + (k - kbeg);
                float4 wa = *(const float4*)wp;
                float4 wb = *(const float4*)(wp + 4);
                acc[j] = fmaf(f8[0], wa.x, acc[j]); acc[j] = fmaf(f8[1], wa.y, acc[j]);
                acc[j] = fmaf(f8[2], wa.z, acc[j]); acc[j] = fmaf(f8[3], wa.w, acc[j]);
                acc[j] = fmaf(f8[4], wb.x, acc[j]); acc[j] = fmaf(f8[5], wb.y, acc[j]);
                acc[j] = fmaf(f8[6], wb.z, acc[j]); acc[j] = fmaf(f8[7], wb.w, acc[j]);
            }
        }
    }

    const int item = kc * 6144 + sub4;
#pragma unroll
    for (int j = 0; j < 4; ++j)
        p[(size_t)(item + j) * 64 + lane] = acc[j];
}

// ------- fused: reduce layer0 partials + update h0,c0 + layer1 features -------
__global__ __launch_bounds__(256) void f01_kernel(
    const float* __restrict__ p, const float* __restrict__ b_ih,
    const float* __restrict__ b_hh,
    float* __restrict__ h0, float* __restrict__ c0, const float* __restrict__ h1,
    float* __restrict__ fz1, float* __restrict__ fs1, float* __restrict__ fb1)
{
    const int g = blockIdx.x * 256 + threadIdx.x;   // 65536 = 1024*64
    const int k = g >> 6, b = g & 63;
    float z;
    if (k < 512) {
        const int o = k;
        auto P = [&](int item) { return p[(size_t)item * 64 + b]; };
        float si = P(o)        + P(6144 + o)        + b_ih[o]        + b_hh[o];
        float sf = P(512 + o)  + P(6144 + 512 + o)  + b_ih[512 + o]  + b_hh[512 + o];
        float sO = P(1024 + o) + P(6144 + 1024 + o) + b_ih[1024 + o] + b_hh[1024 + o];
        float sg = P(1536 + o) + P(6144 + 1536 + o);
#pragma unroll
        for (int r = 0; r < 8; ++r)
            sg += P(2048 + r * 512 + o) + P(6144 + 2048 + r * 512 + o);
        float ig = sigmoidf_(si), fg = sigmoidf_(sf), og = sigmoidf_(sO);
        float c = fg * c0[(size_t)o * 64 + b] + ig * sg;
        c0[(size_t)o * 64 + b] = c;
        z = og * tanhf(c);
        h0[(size_t)o * 64 + b] = z;
    } else {
        z = h1[(size_t)(k - 512) * 64 + b];
    }
    fz1[(size_t)k * 64 + b] = z;
    fs1[(size_t)k * 64 + b] = z / (1.0f + expf(-z));
    float bs[8];
    bspline8(z, bs);
#pragma unroll
    for (int r = 0; r < 8; ++r) fb1[((size_t)k * 8 + r) * 64 + b] = bs[r];
}

// --- fused: reduce layer1 partials + update h1,c1 + layer0 features (t_next) --
__global__ __launch_bounds__(256) void f10_kernel(
    const float* __restrict__ p, const float* __restrict__ b_ih,
    const float* __restrict__ b_hh,
    float* __restrict__ h1, float* __restrict__ c1, const float* __restrict__ h0,
    const float* __restrict__ x, int t_next, int do_feat, int do_red,
    float* __restrict__ fz0, float* __restrict__ fs0, float* __restrict__ fb0)
{
    const int g = blockIdx.x * 256 + threadIdx.x;   // 73728 = 288*256
    if (g < 640 * 64) {
        if (!do_feat) return;
        const int k = g >> 6, b = g & 63;
        float z = (k < 128) ? x[((size_t)b * TT + t_next) * 128 + k]
                            : h0[(size_t)(k - 128) * 64 + b];
        fz0[(size_t)k * 64 + b] = z;
        fs0[(size_t)k * 64 + b] = z / (1.0f + expf(-z));
        float bs[8];
        bspline8(z, bs);
#pragma unroll
        for (int r = 0; r < 8; ++r) fb0[((size_t)k * 8 + r) * 64 + b] = bs[r];
    } else {
        if (!do_red) return;
        const int idx = g - 640 * 64, o = idx >> 6, b = idx & 63;
        auto P = [&](int item) { return p[(size_t)item * 64 + b]; };
        float si = P(o)        + P(6144 + o)        + b_ih[o]        + b_hh[o];
        float sf = P(512 + o)  + P(6144 + 512 + o)  + b_ih[512 + o]  + b_hh[512 + o];
        float sO = P(1024 + o) + P(6144 + 1024 + o) + b_ih[1024 + o] + b_hh[1024 + o];
        float sg = P(1536 + o) + P(6144 + 1536 + o);
#pragma unroll
        for (int r = 0; r < 8; ++r)
            sg += P(2048 + r * 512 + o) + P(6144 + 2048 + r * 512 + o);
        float ig = sigmoidf_(si), fg = sigmoidf_(sf), og = sigmoidf_(sO);
        float c = fg * c1[(size_t)o * 64 + b] + ig * sg;
        c1[(size_t)o * 64 + b] = c;
        h1[(size_t)o * 64 + b] = og * tanhf(c);
    }
}

// out[b][jo] = sum_o h1[o][b] * fc_w[jo][o] + fc_b[jo]  (fp32 out)
__global__ __launch_bounds__(256) void final_fc(
    const float* __restrict__ hT1, const float* __restrict__ fc_w,
    const float* __restrict__ fc_b, float* __restrict__ out)
{
    const int gid = blockIdx.x * 256 + threadIdx.x;   // 8192
    const int b = gid & 63, jo = gid >> 6;
    float a = fc_b[jo];
    for (int o = 0; o < 512; ++o)
        a = fmaf(hT1[(size_t)o * 64 + b], fc_w[(size_t)jo * 512 + o], a);
    out[(size_t)b * 128 + jo] = a;
}

} // namespace

extern "C" void kernel_launch(void* const* d_in, const int* in_sizes, int n_in,
                              void* d_out, int out_size, void* d_ws, size_t ws_size,
                              hipStream_t stream) {
    (void)out_size;
    float* out = (float*)d_out;

    static const int EXP_SIZES[15] = {
        64 * 256 * 128, 1536 * 128, 1536 * 512, 1536, 1536,
        512 * 640, 512 * 640 * 8,
        1536 * 512, 1536 * 512, 1536, 1536,
        512 * 1024, 512 * 1024 * 8,
        128 * 512, 128
    };
    if (n_in != 15) { sentinel_kernel<<<32, 256, 0, stream>>>(out, 111.0f); return; }
    for (int i = 0; i < 15; ++i)
        if (in_sizes[i] != EXP_SIZES[i]) {
            sentinel_kernel<<<32, 256, 0, stream>>>(out, 200.0f * (i + 1)); return;
        }
    if (ws_size < WS_NEED) { sentinel_kernel<<<32, 256, 0, stream>>>(out, 7777.0f); return; }

    const float* x        = (const float*)d_in[0];
    const float* w_ih0    = (const float*)d_in[1];
    const float* w_hh0    = (const float*)d_in[2];
    const float* b_ih0    = (const float*)d_in[3];
    const float* b_hh0    = (const float*)d_in[4];
    const float* kbase0   = (const float*)d_in[5];
    const float* kspline0 = (const float*)d_in[6];
    const float* w_ih1    = (const float*)d_in[7];
    const float* w_hh1    = (const float*)d_in[8];
    const float* b_ih1    = (const float*)d_in[9];
    const float* b_hh1    = (const float*)d_in[10];
    const float* kbase1   = (const float*)d_in[11];
    const float* kspline1 = (const float*)d_in[12];
    const float* fc_w     = (const float*)d_in[13];
    const float* fc_b     = (const float*)d_in[14];

    float* ws   = (float*)d_ws;
    float* h0   = ws + OFF_H0;
    float* c0   = ws + OFF_C0;
    float* h1   = ws + OFF_H1;
    float* c1   = ws + OFF_C1;
    float* fz0  = ws + OFF_FZ0;
    float* fs0  = ws + OFF_FS0;
    float* fb0  = ws + OFF_FB0;
    float* fz1  = ws + OFF_FZ1;
    float* fs1  = ws + OFF_FS1;
    float* fb1  = ws + OFF_FB1;
    float* p    = ws + OFF_P;
    float* swT0 = ws + OFF_SWT0;
    float* swT1 = ws + OFF_SWT1;

    zero_state<<<512, 256, 0, stream>>>(h0);                 // h0,c0,h1,c1
    transpose_sw<640><<<1280, 256, 0, stream>>>(kspline0, swT0);
    transpose_sw<1024><<<2048, 256, 0, stream>>>(kspline1, swT1);
    // initial layer0 features for t=0 (h0 = 0)
    f10_kernel<<<288, 256, 0, stream>>>(p, b_ih1, b_hh1, h1, c1, h0, x,
                                        0, 1, 0, fz0, fs0, fb0);

    for (int t = 0; t < TT; ++t) {
        gemm_kernel<128><<<768, 256, 0, stream>>>(
            fz0, fs0, fb0, w_ih0, w_hh0, kbase0, swT0, p);
        f01_kernel<<<256, 256, 0, stream>>>(
            p, b_ih0, b_hh0, h0, c0, h1, fz1, fs1, fb1);
        gemm_kernel<512><<<768, 256, 0, stream>>>(
            fz1, fs1, fb1, w_ih1, w_hh1, kbase1, swT1, p);
        f10_kernel<<<288, 256, 0, stream>>>(
            p, b_ih1, b_hh1, h1, c1, h0, x, t + 1, (t < TT - 1) ? 1 : 0, 1,
            fz0, fs0, fb0);
    }

    final_fc<<<32, 256, 0, stream>>>(h1, fc_w, fc_b, out);
}